// Round 6
// baseline (812.568 us; speedup 1.0000x reference)
//
#include <hip/hip_runtime.h>
#include <hip/hip_bf16.h>

typedef __bf16 bf16x8 __attribute__((ext_vector_type(8)));
typedef __bf16 bf16x4 __attribute__((ext_vector_type(4)));
typedef float f32x4 __attribute__((ext_vector_type(4)));

#define AS1P(p) ((__attribute__((address_space(1))) void*)(void*)(p))
#define AS3P(p) ((__attribute__((address_space(3))) void*)(p))

// ---------------------------------------------------------------------------
// bf16 GEMM, BK=32 TRIPLE-buffer, depth-2 DMA prefetch, raw-barrier pipeline:
//   C[M,N] = epi( scale * A[M,K] @ Bt[N,K]^T )
// 128x128 block, 4 waves (64x64 quadrants), 48KB LDS -> 3 blocks/CU
// (3 waves/SIMD from DIFFERENT blocks: desynchronized barriers).
// Per iteration: issue tile k+2 (4 DMA/wave), s_waitcnt vmcnt(8) (tile k
// drained; k+1,k+2 in flight ACROSS the barrier), raw s_barrier, 16 mfma,
// lgkmcnt(0) + raw s_barrier.
// Swizzle (row=64B): DMA lane l fetches chunk (l&3)^((l>>3)&3) of row l>>2;
// element (row,c) sits at physical chunk c^((row>>1)&3) -> fragment reads
// cover all 8 bank-quads 2x each => conflict-free (2-way is free).
// ---------------------------------------------------------------------------
__global__ __launch_bounds__(256, 3) void gemm_bt(
    const __hip_bfloat16* __restrict__ A, int lda,
    const __hip_bfloat16* __restrict__ Bt, int ldb,
    int M, int N, int K, int ldc,
    const float* __restrict__ bias, int bias_mode,   // 0 none, 1 per-col, 2 per-row
    float scale,
    const float* __restrict__ residual,              // f32 [M,ldc] or null
    int relu, int causal_skip, int trapezoid, int ksplit,
    float* __restrict__ Cf, __hip_bfloat16* __restrict__ Cb,
    // fused second GEMM (blocks with blockIdx.x >= nsplit1); shares lda/M/K
    int nsplit1, const __hip_bfloat16* __restrict__ A2,
    const __hip_bfloat16* __restrict__ Bt2, int ldb2, int ldc2,
    const float* __restrict__ bias2, __hip_bfloat16* __restrict__ Cb2)
{
    int nb = blockIdx.x;
    if (nsplit1 && nb >= nsplit1) {
        A = A2; Bt = Bt2; ldb = ldb2; ldc = ldc2; bias = bias2;
        Cb = Cb2; Cf = nullptr; residual = nullptr;
        nb -= nsplit1;
    }
    const int m_base = blockIdx.y * 128;
    const int n_base = nb * 128;
    if (causal_skip && (n_base > m_base + 127)) return;   // fully-masked block
    int Kend = K;
    if (trapezoid) { int kl = m_base + 128; Kend = kl < K ? kl : K; }
    int kb = 0, ke = Kend;
    if (ksplit) {
        kb = blockIdx.z * ksplit;
        int k2 = kb + ksplit; ke = k2 < Kend ? k2 : Kend;
        if (kb >= ke) return;                              // empty chunk (trapezoid)
        Cb += (size_t)blockIdx.z * M * ldc;                // bf16 partial slab
        Cf = nullptr;
    }
    const int nt = (ke - kb) >> 5;                         // BK=32 tiles

    // [stage][ A 128x32 (4096 elems) | B 128x32 (4096 elems) ]  = 3 x 16 KB
    __shared__ __align__(16) __hip_bfloat16 Lds[3][8192];

    const int tid  = threadIdx.x;
    const int lane = tid & 63;
    const int wave = tid >> 6;
    const int wm = (wave >> 1) * 64;   // wave's 64x64 quadrant
    const int wn = (wave & 1) * 64;

    f32x4 acc[4][4];
#pragma unroll
    for (int i = 0; i < 4; ++i)
#pragma unroll
        for (int j = 0; j < 4; ++j) acc[i][j] = f32x4{0.f, 0.f, 0.f, 0.f};

    // staging: wave0 A rows 0-63, wave1 A 64-127, wave2 B 0-63, wave3 B 64-127
    const bool isA = wave < 2;
    const __hip_bfloat16* G = isA ? (A + (size_t)m_base * lda) : (Bt + (size_t)n_base * ldb);
    const int ldg = isA ? lda : ldb;
    const int q0 = (wave & 1) * 4;                      // 4 issues per wave
    const int rsub = lane >> 2;                         // row within issue (0..15)
    const int cx   = (lane & 3) ^ ((lane >> 3) & 3);    // swizzled source chunk
    const size_t grow = (size_t)(q0 * 16 + rsub) * ldg + (size_t)cx * 8 + kb;
    const int ldsoff = (isA ? 0 : 4096) + q0 * 512;     // elems, wave-uniform

    const int lrow = lane & 15;                         // m/n within 16x16 fragment
    const int cph  = ((lane >> 4) ^ ((lrow >> 1) & 3)) * 8;  // physical chunk (elems)

#define ISSUE_TILE(KT, STG)                                                      \
    {                                                                            \
        const __hip_bfloat16* g = G + grow + (size_t)(KT) * 32;                  \
        __hip_bfloat16* dst = &Lds[STG][ldsoff];                                 \
        _Pragma("unroll")                                                        \
        for (int q = 0; q < 4; ++q) {                                            \
            __builtin_amdgcn_global_load_lds(AS1P(g), AS3P(dst), 16, 0, 0);      \
            g += (size_t)16 * ldg; dst += 512;                                   \
        }                                                                        \
    }

    ISSUE_TILE(0, 0)
    if (nt > 1) ISSUE_TILE(1, 1)

    int s2 = 2;                                          // (kt+2) % 3
    for (int kt = 0; kt < nt; ++kt) {
        const int cur = (kt == 0) ? 0 : (s2 + 1 >= 3 ? s2 - 2 : s2 + 1);  // kt%3
        if (kt + 2 < nt) {
            ISSUE_TILE(kt + 2, s2)
            __builtin_amdgcn_s_waitcnt(0x0F78);   // vmcnt(8): tile kt drained
        } else if (kt + 1 < nt) {
            __builtin_amdgcn_s_waitcnt(0x0F74);   // vmcnt(4)
        } else {
            __builtin_amdgcn_s_waitcnt(0x0F70);   // vmcnt(0)
        }
        __builtin_amdgcn_sched_barrier(0);
        __builtin_amdgcn_s_barrier();             // raw: no compiler vmcnt(0)

        bf16x8 af[4], bfv[4];
#pragma unroll
        for (int i = 0; i < 4; ++i)
            af[i] = *(const bf16x8*)&Lds[cur][(wm + i * 16 + lrow) * 32 + cph];
#pragma unroll
        for (int j = 0; j < 4; ++j)
            bfv[j] = *(const bf16x8*)&Lds[cur][4096 + (wn + j * 16 + lrow) * 32 + cph];
#pragma unroll
        for (int i = 0; i < 4; ++i)
#pragma unroll
            for (int j = 0; j < 4; ++j)
                acc[i][j] = __builtin_amdgcn_mfma_f32_16x16x32_bf16(af[i], bfv[j], acc[i][j], 0, 0, 0);

        __builtin_amdgcn_s_waitcnt(0xC07F);       // lgkmcnt(0): our ds_reads retired
        __builtin_amdgcn_sched_barrier(0);
        __builtin_amdgcn_s_barrier();             // stage reuse guard
        s2 = (s2 + 1 >= 3) ? 0 : s2 + 1;
    }
#undef ISSUE_TILE

    // epilogue — C/D layout: col = lane&15, row = (lane>>4)*4 + reg
    const int r0 = (lane >> 4) * 4;
    const int c0 = lane & 15;
#pragma unroll
    for (int i = 0; i < 4; ++i) {
#pragma unroll
        for (int j = 0; j < 4; ++j) {
            const int col = n_base + wn + j * 16 + c0;
#pragma unroll
            for (int r = 0; r < 4; ++r) {
                const int row = m_base + wm + i * 16 + r0 + r;
                float v = acc[i][j][r] * scale;
                if (bias_mode == 1) v += bias[col];
                else if (bias_mode == 2) v += bias[row];
                if (relu) v = fmaxf(v, 0.f);
                const size_t idx = (size_t)row * ldc + col;
                if (residual) v += residual[idx];
                if (Cf) Cf[idx] = v;
                else    Cb[idx] = __float2bfloat16(v);
            }
        }
    }
}

// ---------------------------------------------------------------------------
// Split-K reducer over bf16 partials: C = epi( sum_z Pb[z] )
// ---------------------------------------------------------------------------
__global__ __launch_bounds__(256) void reduce_k_kernel(
    const __hip_bfloat16* __restrict__ Pb, int M, int N, int nsplit, int KC, int trapK,
    const float* __restrict__ bias, const float* __restrict__ residual,
    float* __restrict__ Cf, __hip_bfloat16* __restrict__ Cb)
{
    const int idx = blockIdx.x * 256 + threadIdx.x;      // one per 4 elems
    const int nv = N >> 2;
    const int row = idx / nv;
    if (row >= M) return;
    const int c4 = (idx - row * nv) * 4;
    int nc = nsplit;
    if (trapK) {
        int kend = (row & ~127) + 128; if (kend > trapK) kend = trapK;
        nc = (kend + KC - 1) / KC;
    }
    float s0 = 0.f, s1 = 0.f, s2 = 0.f, s3 = 0.f;
    for (int c = 0; c < nc; ++c) {
        const bf16x4 p = *(const bf16x4*)(Pb + ((size_t)c * M + row) * N + c4);
        s0 += (float)p[0]; s1 += (float)p[1]; s2 += (float)p[2]; s3 += (float)p[3];
    }
    if (bias) {
        const f32x4 b = *(const f32x4*)(bias + c4);
        s0 += b[0]; s1 += b[1]; s2 += b[2]; s3 += b[3];
    }
    if (residual) {
        const f32x4 rv = *(const f32x4*)(residual + (size_t)row * N + c4);
        s0 += rv[0]; s1 += rv[1]; s2 += rv[2]; s3 += rv[3];
    }
    if (Cf) { f32x4 o = {s0, s1, s2, s3}; *(f32x4*)(Cf + (size_t)row * N + c4) = o; }
    else {
        bf16x4 o = { (__bf16)s0, (__bf16)s1, (__bf16)s2, (__bf16)s3 };
        *(bf16x4*)(Cb + (size_t)row * N + c4) = o;
    }
}

// ---------------------------------------------------------------------------
// f32 -> bf16 convert (4 elems/thread)
// ---------------------------------------------------------------------------
__global__ __launch_bounds__(256) void convert_bf16_kernel(
    const float* __restrict__ x, __hip_bfloat16* __restrict__ y, int n4)
{
    const int i = blockIdx.x * 256 + threadIdx.x;
    if (i >= n4) return;
    const float4 v = ((const float4*)x)[i];
    bf16x4 o = { (__bf16)v.x, (__bf16)v.y, (__bf16)v.z, (__bf16)v.w };
    *(bf16x4*)(y + (size_t)i * 4) = o;
}

// ---------------------------------------------------------------------------
// W[K,N] f32  ->  Wt[N,K] bf16   (32x32 LDS tile, padded)
// ---------------------------------------------------------------------------
__global__ __launch_bounds__(256) void transpose_convert_kernel(
    const float* __restrict__ W, __hip_bfloat16* __restrict__ Wt, int K, int N)
{
    __shared__ float t[32][33];
    const int k0 = blockIdx.y * 32;
    const int n0 = blockIdx.x * 32;
    const int tx = threadIdx.x;
    for (int i = threadIdx.y; i < 32; i += 8)
        t[i][tx] = W[(size_t)(k0 + i) * N + n0 + tx];
    __syncthreads();
    for (int i = threadIdx.y; i < 32; i += 8)
        Wt[(size_t)(n0 + i) * K + k0 + tx] = __float2bfloat16(t[tx][i]);
}

// ---------------------------------------------------------------------------
// bf16 transpose: dst[c][r] = src[r][c]
// ---------------------------------------------------------------------------
__global__ __launch_bounds__(256) void transpose_bf16_kernel(
    const __hip_bfloat16* __restrict__ src, int ls,
    __hip_bfloat16* __restrict__ dst, int ld)
{
    __shared__ __hip_bfloat16 t[32][33];
    const int r0 = blockIdx.y * 32;
    const int c0 = blockIdx.x * 32;
    const int tx = threadIdx.x;
    for (int i = threadIdx.y; i < 32; i += 8)
        t[i][tx] = src[(size_t)(r0 + i) * ls + c0 + tx];
    __syncthreads();
    for (int i = threadIdx.y; i < 32; i += 8)
        dst[(size_t)(c0 + i) * ld + r0 + tx] = t[tx][i];
}

// ---------------------------------------------------------------------------
// Row softmax over bf16 S: A = softmax(S) (bf16 out); causal masks j>row.
// Zero-fill only to the 128-row trapezoid boundary (AV reads no further).
// ---------------------------------------------------------------------------
__global__ __launch_bounds__(256) void softmax_kernel(
    const __hip_bfloat16* __restrict__ S, __hip_bfloat16* __restrict__ A, int N, int causal)
{
    __shared__ float sm[4];
    const int row = blockIdx.x;
    const int tid = threadIdx.x;
    const int limit = causal ? (row + 1) : N;
    const int zlimit = causal ? (((row & ~127) + 128) < N ? ((row & ~127) + 128) : N) : N;
    const __hip_bfloat16* Srow = S + (size_t)row * N;
    __hip_bfloat16* Arow = A + (size_t)row * N;
    const int nv = limit >> 2;

    float m = -3.0e38f;
    for (int v = tid; v < nv; v += 256) {
        const bf16x4 x = *(const bf16x4*)(Srow + (size_t)v * 4);
        m = fmaxf(m, fmaxf(fmaxf((float)x[0], (float)x[1]), fmaxf((float)x[2], (float)x[3])));
    }
    for (int j = (nv << 2) + tid; j < limit; j += 256) m = fmaxf(m, (float)Srow[j]);
#pragma unroll
    for (int o = 32; o; o >>= 1) m = fmaxf(m, __shfl_down(m, o));
    if ((tid & 63) == 0) sm[tid >> 6] = m;
    __syncthreads();
    m = fmaxf(fmaxf(sm[0], sm[1]), fmaxf(sm[2], sm[3]));
    __syncthreads();

    float s = 0.f;
    for (int v = tid; v < nv; v += 256) {
        const bf16x4 x = *(const bf16x4*)(Srow + (size_t)v * 4);
        s += __expf((float)x[0] - m) + __expf((float)x[1] - m)
           + __expf((float)x[2] - m) + __expf((float)x[3] - m);
    }
    for (int j = (nv << 2) + tid; j < limit; j += 256) s += __expf((float)Srow[j] - m);
#pragma unroll
    for (int o = 32; o; o >>= 1) s += __shfl_down(s, o);
    if ((tid & 63) == 0) sm[tid >> 6] = s;
    __syncthreads();
    s = sm[0] + sm[1] + sm[2] + sm[3];
    const float inv = 1.f / s;

    for (int v = tid; v < nv; v += 256) {
        const bf16x4 x = *(const bf16x4*)(Srow + (size_t)v * 4);
        bf16x4 o = { (__bf16)(__expf((float)x[0] - m) * inv), (__bf16)(__expf((float)x[1] - m) * inv),
                     (__bf16)(__expf((float)x[2] - m) * inv), (__bf16)(__expf((float)x[3] - m) * inv) };
        *(bf16x4*)(Arow + (size_t)v * 4) = o;
    }
    for (int j = (nv << 2) + tid; j < limit; j += 256)
        Arow[j] = __float2bfloat16(__expf((float)Srow[j] - m) * inv);
    const __hip_bfloat16 z = __float2bfloat16(0.f);
    for (int j = limit + tid; j < zlimit; j += 256) Arow[j] = z;
}

// ---------------------------------------------------------------------------
// Row LayerNorm over 1024: writes f32 (always) + bf16 (optional)
// ---------------------------------------------------------------------------
__global__ __launch_bounds__(256) void layernorm_kernel(
    const float* __restrict__ X, const float* __restrict__ g, const float* __restrict__ b,
    float* __restrict__ outF, __hip_bfloat16* __restrict__ outB)
{
    __shared__ float sm[8];
    const int row = blockIdx.x;
    const int tid = threadIdx.x;
    const float4 v = ((const float4*)(X + (size_t)row * 1024))[tid];
    float s  = v.x + v.y + v.z + v.w;
    float ss = v.x * v.x + v.y * v.y + v.z * v.z + v.w * v.w;
#pragma unroll
    for (int o = 32; o; o >>= 1) { s += __shfl_down(s, o); ss += __shfl_down(ss, o); }
    if ((tid & 63) == 0) { sm[tid >> 6] = s; sm[4 + (tid >> 6)] = ss; }
    __syncthreads();
    s  = sm[0] + sm[1] + sm[2] + sm[3];
    ss = sm[4] + sm[5] + sm[6] + sm[7];
    const float mu   = s * (1.f / 1024.f);
    const float var  = ss * (1.f / 1024.f) - mu * mu;
    const float rstd = rsqrtf(var + 1e-5f);
    const float4 gv = ((const float4*)g)[tid];
    const float4 bv = ((const float4*)b)[tid];
    float4 o;
    o.x = (v.x - mu) * rstd * gv.x + bv.x;
    o.y = (v.y - mu) * rstd * gv.y + bv.y;
    o.z = (v.z - mu) * rstd * gv.z + bv.z;
    o.w = (v.w - mu) * rstd * gv.w + bv.w;
    ((float4*)(outF + (size_t)row * 1024))[tid] = o;
    if (outB) {
        bf16x4 ob = { (__bf16)o.x, (__bf16)o.y, (__bf16)o.z, (__bf16)o.w };
        *(bf16x4*)(outB + (size_t)row * 1024 + (size_t)tid * 4) = ob;
    }
}

// ---------------------------------------------------------------------------
// Launch
// ---------------------------------------------------------------------------
extern "C" void kernel_launch(void* const* d_in, const int* in_sizes, int n_in,
                              void* d_out, int out_size, void* d_ws, size_t ws_size,
                              hipStream_t stream)
{
    const int M = 4096, Pd = 1024, DFF = 4096, NS = 4096;
    const size_t MB = 1024 * 1024;

    const float* Y   = (const float*)d_in[0];
    const float* Xp  = (const float*)d_in[1];
    const float* wq1 = (const float*)d_in[2];  const float* bq1 = (const float*)d_in[3];
    const float* wk1 = (const float*)d_in[4];  const float* bk1 = (const float*)d_in[5];
    const float* wv1 = (const float*)d_in[6];  const float* bv1 = (const float*)d_in[7];
    const float* w0  = (const float*)d_in[8];  const float* b0  = (const float*)d_in[9];
    const float* g1  = (const float*)d_in[10]; const float* be1 = (const float*)d_in[11];
    const float* wq2 = (const float*)d_in[12]; const float* bq2 = (const float*)d_in[13];
    const float* wk2 = (const float*)d_in[14]; const float* bk2 = (const float*)d_in[15];
    const float* wv2 = (const float*)d_in[16]; const float* bv2 = (const float*)d_in[17];
    const float* w1  = (const float*)d_in[18]; const float* b1  = (const float*)d_in[19];
    const float* g2  = (const float*)d_in[20]; const float* be2 = (const float*)d_in[21];
    const float* w2  = (const float*)d_in[22]; const float* b2  = (const float*)d_in[23];
    const float* w3  = (const float*)d_in[24]; const float* b3  = (const float*)d_in[25];
    const float* g3  = (const float*)d_in[26]; const float* be3 = (const float*)d_in[27];

    // ---- workspace layout (MB offsets; lifetimes checked) ----
    char* ws = (char*)d_ws;
    __hip_bfloat16* Ybf   = (__hip_bfloat16*)(ws + 0 * MB);    // dead after QKV1 -> Ubf
    __hip_bfloat16* Ubf   = (__hip_bfloat16*)(ws + 0 * MB);
    __hip_bfloat16* Xpbf  = (__hip_bfloat16*)(ws + 8 * MB);    // dead after KV2 -> AVbf/Qbf
    __hip_bfloat16* AVbf  = (__hip_bfloat16*)(ws + 8 * MB);
    __hip_bfloat16* Qbf   = (__hip_bfloat16*)(ws + 8 * MB);
    __hip_bfloat16* wqkv1t= (__hip_bfloat16*)(ws + 16 * MB);   // [3072,1024]
    __hip_bfloat16* w0t   = (__hip_bfloat16*)(ws + 22 * MB);
    __hip_bfloat16* wq2t  = (__hip_bfloat16*)(ws + 24 * MB);
    __hip_bfloat16* wkv2t = (__hip_bfloat16*)(ws + 26 * MB);   // [2048,1024]
    __hip_bfloat16* w1t   = (__hip_bfloat16*)(ws + 30 * MB);
    __hip_bfloat16* w2t   = (__hip_bfloat16*)(ws + 32 * MB);   // [4096,1024]
    __hip_bfloat16* w3t   = (__hip_bfloat16*)(ws + 40 * MB);   // [1024,4096]
    float*          bqkv1 = (float*)(ws + 48 * MB);            // [3072]
    float*          bkv2  = (float*)(ws + 48 * MB + 512 * 1024);// [2048]
    __hip_bfloat16* QKV1  = (__hip_bfloat16*)(ws + 49 * MB);   // [4096,3072]
    __hip_bfloat16* KV2   = (__hip_bfloat16*)(ws + 73 * MB);   // [4096,2048]
    __hip_bfloat16* Vt    = (__hip_bfloat16*)(ws + 89 * MB);   // [1024,4096]
    __hip_bfloat16* Sb    = (__hip_bfloat16*)(ws + 97 * MB);   // [4096,4096] bf16 (32MB)
    __hip_bfloat16* Pb    = (__hip_bfloat16*)(ws + 97 * MB);   // splitK bf16 partials overlay (Sb dead)
    __hip_bfloat16* Abf   = (__hip_bfloat16*)(ws + 161 * MB);  // [4096,4096] bf16 (32MB), also H
    float*          Xres  = (float*)(ws + 193 * MB);           // [4096,1024] f32
    float*          Uf    = (float*)(ws + 209 * MB);           // [4096,1024] f32
    float*          Out   = (float*)d_out;
    if (ws_size < 225 * MB) return;

    auto cvt = [&](const float* src, __hip_bfloat16* dst, int n) {
        convert_bf16_kernel<<<dim3(n / 1024), dim3(256), 0, stream>>>(src, dst, n / 4);
    };
    auto tconv = [&](const float* W, __hip_bfloat16* Wt, int K, int N) {
        transpose_convert_kernel<<<dim3(N / 32, K / 32), dim3(32, 8), 0, stream>>>(W, Wt, K, N);
    };
    auto tbf = [&](const __hip_bfloat16* src, int ls, __hip_bfloat16* dst, int ld, int R, int C) {
        transpose_bf16_kernel<<<dim3(C / 32, R / 32), dim3(32, 8), 0, stream>>>(src, ls, dst, ld);
    };
    auto gemm = [&](const __hip_bfloat16* A, int lda, const __hip_bfloat16* Bt, int ldb,
                    int Mm, int Nn, int Kk, int ldc,
                    const float* bias, int bmode, float scale, const float* res,
                    int relu, int causal, int trap, int ksplit,
                    float* Cf, __hip_bfloat16* Cb) {
        const int nz = ksplit ? (Kk + ksplit - 1) / ksplit : 1;
        gemm_bt<<<dim3(Nn / 128, Mm / 128, nz), dim3(256), 0, stream>>>(
            A, lda, Bt, ldb, Mm, Nn, Kk, ldc, bias, bmode, scale, res, relu, causal, trap, ksplit,
            Cf, Cb, 0, nullptr, nullptr, 0, 0, nullptr, nullptr);
    };
    auto reduce = [&](const __hip_bfloat16* P, int Mm, int Nn, int nsplit, int KC, int trapK,
                      const float* bias, const float* res, float* Cf, __hip_bfloat16* Cb) {
        reduce_k_kernel<<<dim3(Mm * Nn / 1024), dim3(256), 0, stream>>>(
            P, Mm, Nn, nsplit, KC, trapK, bias, res, Cf, Cb);
    };

    const float scl = 0.03125f;  // 1/sqrt(1024)

    // --- prep ---
    cvt(Y,  Ybf,  M * Pd);
    cvt(Xp, Xpbf, NS * Pd);
    tconv(wq1, wqkv1t,            Pd, Pd);
    tconv(wk1, wqkv1t + Pd * Pd,  Pd, Pd);
    tconv(wv1, wqkv1t + 2*Pd*Pd,  Pd, Pd);
    tconv(w0,  w0t,  Pd, Pd);
    tconv(wq2, wq2t, Pd, Pd);
    tconv(wk2, wkv2t,           Pd, Pd);
    tconv(wv2, wkv2t + Pd * Pd, Pd, Pd);
    tconv(w1,  w1t,  Pd, Pd);
    tconv(w2, w2t, Pd, DFF);
    tconv(w3, w3t, DFF, Pd);
    hipMemcpyAsync(bqkv1,            bq1, Pd * 4, hipMemcpyDeviceToDevice, stream);
    hipMemcpyAsync(bqkv1 + Pd,       bk1, Pd * 4, hipMemcpyDeviceToDevice, stream);
    hipMemcpyAsync(bqkv1 + 2 * Pd,   bv1, Pd * 4, hipMemcpyDeviceToDevice, stream);
    hipMemcpyAsync(bkv2,             bk2, Pd * 4, hipMemcpyDeviceToDevice, stream);
    hipMemcpyAsync(bkv2 + Pd,        bv2, Pd * 4, hipMemcpyDeviceToDevice, stream);

    // --- merged projections: QKV1 (24 n-blocks) + KV2 (16 n-blocks) ---
    gemm_bt<<<dim3(40, 32, 1), dim3(256), 0, stream>>>(
        Ybf, Pd, wqkv1t, Pd, M, 3072, Pd, 3072, bqkv1, 1, 1.f, nullptr, 0, 0, 0, 0,
        nullptr, QKV1,
        24, Xpbf, wkv2t, Pd, 2048, bkv2, KV2);

    // --- masked self-attention ---
    tbf(QKV1 + 2048, 3072, Vt, M, M, Pd);                       // V1 -> Vt [1024,4096]
    gemm(QKV1, 3072, QKV1 + 1024, 3072, M, M, Pd, M,
         nullptr, 0, scl, nullptr, 0, 1, 0, 0, nullptr, Sb);    // causal S (bf16)
    softmax_kernel<<<dim3(M), dim3(256), 0, stream>>>(Sb, Abf, M, 1);
    gemm(Abf, M, Vt, M, M, Pd, M, Pd,
         nullptr, 0, 1.f, nullptr, 0, 0, 1, 1024, nullptr, Pb); // AV1 splitK=4, trapezoid
    reduce(Pb, M, Pd, 4, 1024, M, nullptr, nullptr, nullptr, AVbf);
    gemm(AVbf, Pd, w0t, Pd, M, Pd, Pd, Pd, b0, 1, 1.f, Y, 0, 0, 0, 0, Xres, nullptr);
    layernorm_kernel<<<dim3(M), dim3(256), 0, stream>>>(Xres, g1, be1, Uf, Ubf);

    // --- cross-attention ---
    gemm(Ubf, Pd, wq2t, Pd, M, Pd, Pd, Pd, bq2, 1, 1.f, nullptr, 0, 0, 0, 0, nullptr, Qbf);
    tbf(KV2 + 1024, 2048, Vt, NS, NS, Pd);                      // V2 -> Vt [1024,4096]
    gemm(Qbf, Pd, KV2, 2048, M, NS, Pd, NS,
         nullptr, 0, scl, nullptr, 0, 0, 0, 0, nullptr, Sb);    // S2 full (bf16)
    softmax_kernel<<<dim3(M), dim3(256), 0, stream>>>(Sb, Abf, NS, 0);
    gemm(Abf, NS, Vt, NS, M, Pd, NS, Pd,
         nullptr, 0, 1.f, nullptr, 0, 0, 0, 1024, nullptr, Pb); // AV2 splitK=4
    reduce(Pb, M, Pd, 4, 1024, 0, nullptr, nullptr, nullptr, AVbf);
    gemm(AVbf, Pd, w1t, Pd, M, Pd, Pd, Pd, b1, 1, 1.f, Uf, 0, 0, 0, 0, Xres, nullptr);
    layernorm_kernel<<<dim3(M), dim3(256), 0, stream>>>(Xres, g2, be2, Uf, Ubf);

    // --- FFN ---
    gemm(Ubf, Pd, w2t, Pd, M, DFF, Pd, DFF, b2, 1, 1.f, nullptr, 1, 0, 0, 0, nullptr, Abf);
    gemm(Abf, DFF, w3t, DFF, M, Pd, DFF, Pd,
         nullptr, 0, 1.f, nullptr, 0, 0, 0, 1024, nullptr, Pb); // FFN2 splitK=4
    reduce(Pb, M, Pd, 4, 1024, 0, b3, Uf, Xres, nullptr);
    layernorm_kernel<<<dim3(M), dim3(256), 0, stream>>>(Xres, g3, be3, Out, nullptr);
}

// Round 7
// 777.960 us; speedup vs baseline: 1.0445x; 1.0445x over previous
//
#include <hip/hip_runtime.h>
#include <hip/hip_bf16.h>

typedef __bf16 bf16x8 __attribute__((ext_vector_type(8)));
typedef __bf16 bf16x4 __attribute__((ext_vector_type(4)));
typedef float f32x4 __attribute__((ext_vector_type(4)));

#define AS1P(p) ((__attribute__((address_space(1))) void*)(void*)(p))
#define AS3P(p) ((__attribute__((address_space(3))) void*)(p))

// ---------------------------------------------------------------------------
// bf16 GEMM, BK=32 triple-buffer, depth-2 prefetch, SINGLE-barrier K-loop:
//   per iter: [vmcnt(4) -> s_barrier -> issue tile k+2 -> compute tile k]
// vmcnt BEFORE the barrier publishes every wave's tile-k loads at the
// rendezvous; issue AFTER the barrier is ordered against segment-(k-1)
// readers of the same stage (their ds_reads were consumed by MFMAs before
// they arrived). One barrier, no lgkmcnt drain -> half R6's sync cost.
// XCD swizzle: id&7 (round-robin XCD) owns a gx/4 x gy/2 region for L2
// locality. LDS chunk-XOR swizzle keeps fragment reads <=2-way (free).
// ---------------------------------------------------------------------------
__global__ __launch_bounds__(256, 3) void gemm_bt(
    const __hip_bfloat16* __restrict__ A, int lda,
    const __hip_bfloat16* __restrict__ Bt, int ldb,
    int M, int N, int K, int ldc,
    const float* __restrict__ bias, int bias_mode,   // 0 none, 1 per-col, 2 per-row
    float scale,
    const float* __restrict__ residual,              // f32 [M,ldc] or null
    int relu, int causal_skip, int trapezoid, int ksplit,
    float* __restrict__ Cf, __hip_bfloat16* __restrict__ Cb,
    // fused second GEMM (blocks with nb >= nsplit1); shares lda/M/K
    int nsplit1, const __hip_bfloat16* __restrict__ A2,
    const __hip_bfloat16* __restrict__ Bt2, int ldb2, int ldc2,
    const float* __restrict__ bias2, __hip_bfloat16* __restrict__ Cb2)
{
    int nb = blockIdx.x;
    int mb = blockIdx.y;
    {   // XCD-aware 2D-region swizzle (identity if shape not divisible)
        const int gx = gridDim.x, gy = gridDim.y;
        if ((gx & 3) == 0 && (gy & 1) == 0) {
            const int id = mb * gx + nb;
            const int X  = id & 7;          // round-robin XCD id
            const int L  = id >> 3;
            const int rn = gx >> 2, rm = gy >> 1;
            const int nb_l = L / rm, mb_l = L - nb_l * rm;
            nb = (X & 3) * rn + nb_l;
            mb = (X >> 2) * rm + mb_l;
        }
    }
    if (nsplit1 && nb >= nsplit1) {
        A = A2; Bt = Bt2; ldb = ldb2; ldc = ldc2; bias = bias2;
        Cb = Cb2; Cf = nullptr; residual = nullptr;
        nb -= nsplit1;
    }
    const int m_base = mb * 128;
    const int n_base = nb * 128;
    if (causal_skip && (n_base > m_base + 127)) return;   // fully-masked block
    int Kend = K;
    if (trapezoid) { int kl = m_base + 128; Kend = kl < K ? kl : K; }
    int kb = 0, ke = Kend;
    if (ksplit) {
        kb = blockIdx.z * ksplit;
        int k2 = kb + ksplit; ke = k2 < Kend ? k2 : Kend;
        if (kb >= ke) return;                              // empty chunk (trapezoid)
        Cb += (size_t)blockIdx.z * M * ldc;                // bf16 partial slab
        Cf = nullptr;
    }
    const int nt = (ke - kb) >> 5;                         // BK=32 tiles

    // [stage][ A 128x32 (4096 elems) | B 128x32 (4096 elems) ]  = 3 x 16 KB
    __shared__ __align__(16) __hip_bfloat16 Lds[3][8192];

    const int tid  = threadIdx.x;
    const int lane = tid & 63;
    const int wave = tid >> 6;
    const int wm = (wave >> 1) * 64;   // wave's 64x64 quadrant
    const int wn = (wave & 1) * 64;

    f32x4 acc[4][4];
#pragma unroll
    for (int i = 0; i < 4; ++i)
#pragma unroll
        for (int j = 0; j < 4; ++j) acc[i][j] = f32x4{0.f, 0.f, 0.f, 0.f};

    // staging: wave0 A rows 0-63, wave1 A 64-127, wave2 B 0-63, wave3 B 64-127
    const bool isA = wave < 2;
    const __hip_bfloat16* G = isA ? (A + (size_t)m_base * lda) : (Bt + (size_t)n_base * ldb);
    const int ldg = isA ? lda : ldb;
    const int q0 = (wave & 1) * 4;                      // 4 issues per wave
    const int rsub = lane >> 2;                         // row within issue (0..15)
    const int cx   = (lane & 3) ^ ((lane >> 3) & 3);    // swizzled source chunk
    const size_t grow = (size_t)(q0 * 16 + rsub) * ldg + (size_t)cx * 8 + kb;
    const int ldsoff = (isA ? 0 : 4096) + q0 * 512;     // elems, wave-uniform

    const int lrow = lane & 15;                         // m/n within 16x16 fragment
    const int cph  = ((lane >> 4) ^ ((lrow >> 1) & 3)) * 8;  // physical chunk (elems)

#define ISSUE_TILE(KT, STG)                                                      \
    {                                                                            \
        const __hip_bfloat16* g = G + grow + (size_t)(KT) * 32;                  \
        __hip_bfloat16* dst = &Lds[STG][ldsoff];                                 \
        _Pragma("unroll")                                                        \
        for (int q = 0; q < 4; ++q) {                                            \
            __builtin_amdgcn_global_load_lds(AS1P(g), AS3P(dst), 16, 0, 0);      \
            g += (size_t)16 * ldg; dst += 512;                                   \
        }                                                                        \
    }

    ISSUE_TILE(0, 0)
    if (nt > 1) ISSUE_TILE(1, 1)

    int cur = 0;
    for (int kt = 0; kt < nt; ++kt) {
        __builtin_amdgcn_sched_barrier(0);
        if (kt + 1 < nt) __builtin_amdgcn_s_waitcnt(0x0F74);  // vmcnt(4): tile kt drained
        else             __builtin_amdgcn_s_waitcnt(0x0F70);  // vmcnt(0): last tile
        __builtin_amdgcn_sched_barrier(0);
        __builtin_amdgcn_s_barrier();             // single rendezvous per iteration
        __builtin_amdgcn_sched_barrier(0);
        if (kt + 2 < nt) {
            int s2 = cur + 2; if (s2 >= 3) s2 -= 3;
            ISSUE_TILE(kt + 2, s2)
        }

        bf16x8 af[4], bfv[4];
#pragma unroll
        for (int i = 0; i < 4; ++i)
            af[i] = *(const bf16x8*)&Lds[cur][(wm + i * 16 + lrow) * 32 + cph];
#pragma unroll
        for (int j = 0; j < 4; ++j)
            bfv[j] = *(const bf16x8*)&Lds[cur][4096 + (wn + j * 16 + lrow) * 32 + cph];
#pragma unroll
        for (int i = 0; i < 4; ++i)
#pragma unroll
            for (int j = 0; j < 4; ++j)
                acc[i][j] = __builtin_amdgcn_mfma_f32_16x16x32_bf16(af[i], bfv[j], acc[i][j], 0, 0, 0);

        cur = (cur + 1 == 3) ? 0 : cur + 1;
    }
#undef ISSUE_TILE

    // epilogue — C/D layout: col = lane&15, row = (lane>>4)*4 + reg
    const int r0 = (lane >> 4) * 4;
    const int c0 = lane & 15;
#pragma unroll
    for (int i = 0; i < 4; ++i) {
#pragma unroll
        for (int j = 0; j < 4; ++j) {
            const int col = n_base + wn + j * 16 + c0;
#pragma unroll
            for (int r = 0; r < 4; ++r) {
                const int row = m_base + wm + i * 16 + r0 + r;
                float v = acc[i][j][r] * scale;
                if (bias_mode == 1) v += bias[col];
                else if (bias_mode == 2) v += bias[row];
                if (relu) v = fmaxf(v, 0.f);
                const size_t idx = (size_t)row * ldc + col;
                if (residual) v += residual[idx];
                if (Cf) Cf[idx] = v;
                else    Cb[idx] = __float2bfloat16(v);
            }
        }
    }
}

// ---------------------------------------------------------------------------
// Split-K reducer over bf16 partials: C = epi( sum_z Pb[z] )
// ---------------------------------------------------------------------------
__global__ __launch_bounds__(256) void reduce_k_kernel(
    const __hip_bfloat16* __restrict__ Pb, int M, int N, int nsplit, int KC, int trapK,
    const float* __restrict__ bias, const float* __restrict__ residual,
    float* __restrict__ Cf, __hip_bfloat16* __restrict__ Cb)
{
    const int idx = blockIdx.x * 256 + threadIdx.x;      // one per 4 elems
    const int nv = N >> 2;
    const int row = idx / nv;
    if (row >= M) return;
    const int c4 = (idx - row * nv) * 4;
    int nc = nsplit;
    if (trapK) {
        int kend = (row & ~127) + 128; if (kend > trapK) kend = trapK;
        nc = (kend + KC - 1) / KC;
    }
    float s0 = 0.f, s1 = 0.f, s2 = 0.f, s3 = 0.f;
    for (int c = 0; c < nc; ++c) {
        const bf16x4 p = *(const bf16x4*)(Pb + ((size_t)c * M + row) * N + c4);
        s0 += (float)p[0]; s1 += (float)p[1]; s2 += (float)p[2]; s3 += (float)p[3];
    }
    if (bias) {
        const f32x4 b = *(const f32x4*)(bias + c4);
        s0 += b[0]; s1 += b[1]; s2 += b[2]; s3 += b[3];
    }
    if (residual) {
        const f32x4 rv = *(const f32x4*)(residual + (size_t)row * N + c4);
        s0 += rv[0]; s1 += rv[1]; s2 += rv[2]; s3 += rv[3];
    }
    if (Cf) { f32x4 o = {s0, s1, s2, s3}; *(f32x4*)(Cf + (size_t)row * N + c4) = o; }
    else {
        bf16x4 o = { (__bf16)s0, (__bf16)s1, (__bf16)s2, (__bf16)s3 };
        *(bf16x4*)(Cb + (size_t)row * N + c4) = o;
    }
}

// ---------------------------------------------------------------------------
// f32 -> bf16 convert (4 elems/thread)
// ---------------------------------------------------------------------------
__global__ __launch_bounds__(256) void convert_bf16_kernel(
    const float* __restrict__ x, __hip_bfloat16* __restrict__ y, int n4)
{
    const int i = blockIdx.x * 256 + threadIdx.x;
    if (i >= n4) return;
    const float4 v = ((const float4*)x)[i];
    bf16x4 o = { (__bf16)v.x, (__bf16)v.y, (__bf16)v.z, (__bf16)v.w };
    *(bf16x4*)(y + (size_t)i * 4) = o;
}

// ---------------------------------------------------------------------------
// W[K,N] f32  ->  Wt[N,K] bf16   (32x32 LDS tile, padded)
// ---------------------------------------------------------------------------
__global__ __launch_bounds__(256) void transpose_convert_kernel(
    const float* __restrict__ W, __hip_bfloat16* __restrict__ Wt, int K, int N)
{
    __shared__ float t[32][33];
    const int k0 = blockIdx.y * 32;
    const int n0 = blockIdx.x * 32;
    const int tx = threadIdx.x;
    for (int i = threadIdx.y; i < 32; i += 8)
        t[i][tx] = W[(size_t)(k0 + i) * N + n0 + tx];
    __syncthreads();
    for (int i = threadIdx.y; i < 32; i += 8)
        Wt[(size_t)(n0 + i) * K + k0 + tx] = __float2bfloat16(t[tx][i]);
}

// ---------------------------------------------------------------------------
// bf16 transpose: dst[c][r] = src[r][c]
// ---------------------------------------------------------------------------
__global__ __launch_bounds__(256) void transpose_bf16_kernel(
    const __hip_bfloat16* __restrict__ src, int ls,
    __hip_bfloat16* __restrict__ dst, int ld)
{
    __shared__ __hip_bfloat16 t[32][33];
    const int r0 = blockIdx.y * 32;
    const int c0 = blockIdx.x * 32;
    const int tx = threadIdx.x;
    for (int i = threadIdx.y; i < 32; i += 8)
        t[i][tx] = src[(size_t)(r0 + i) * ls + c0 + tx];
    __syncthreads();
    for (int i = threadIdx.y; i < 32; i += 8)
        dst[(size_t)(c0 + i) * ld + r0 + tx] = t[tx][i];
}

// ---------------------------------------------------------------------------
// Row softmax over bf16 S: A = softmax(S) (bf16 out); causal masks j>row.
// Zero-fill only to the 128-row trapezoid boundary (AV reads no further).
// ---------------------------------------------------------------------------
__global__ __launch_bounds__(256) void softmax_kernel(
    const __hip_bfloat16* __restrict__ S, __hip_bfloat16* __restrict__ A, int N, int causal)
{
    __shared__ float sm[4];
    const int row = blockIdx.x;
    const int tid = threadIdx.x;
    const int limit = causal ? (row + 1) : N;
    const int zlimit = causal ? (((row & ~127) + 128) < N ? ((row & ~127) + 128) : N) : N;
    const __hip_bfloat16* Srow = S + (size_t)row * N;
    __hip_bfloat16* Arow = A + (size_t)row * N;
    const int nv = limit >> 2;

    float m = -3.0e38f;
    for (int v = tid; v < nv; v += 256) {
        const bf16x4 x = *(const bf16x4*)(Srow + (size_t)v * 4);
        m = fmaxf(m, fmaxf(fmaxf((float)x[0], (float)x[1]), fmaxf((float)x[2], (float)x[3])));
    }
    for (int j = (nv << 2) + tid; j < limit; j += 256) m = fmaxf(m, (float)Srow[j]);
#pragma unroll
    for (int o = 32; o; o >>= 1) m = fmaxf(m, __shfl_down(m, o));
    if ((tid & 63) == 0) sm[tid >> 6] = m;
    __syncthreads();
    m = fmaxf(fmaxf(sm[0], sm[1]), fmaxf(sm[2], sm[3]));
    __syncthreads();

    float s = 0.f;
    for (int v = tid; v < nv; v += 256) {
        const bf16x4 x = *(const bf16x4*)(Srow + (size_t)v * 4);
        s += __expf((float)x[0] - m) + __expf((float)x[1] - m)
           + __expf((float)x[2] - m) + __expf((float)x[3] - m);
    }
    for (int j = (nv << 2) + tid; j < limit; j += 256) s += __expf((float)Srow[j] - m);
#pragma unroll
    for (int o = 32; o; o >>= 1) s += __shfl_down(s, o);
    if ((tid & 63) == 0) sm[tid >> 6] = s;
    __syncthreads();
    s = sm[0] + sm[1] + sm[2] + sm[3];
    const float inv = 1.f / s;

    for (int v = tid; v < nv; v += 256) {
        const bf16x4 x = *(const bf16x4*)(Srow + (size_t)v * 4);
        bf16x4 o = { (__bf16)(__expf((float)x[0] - m) * inv), (__bf16)(__expf((float)x[1] - m) * inv),
                     (__bf16)(__expf((float)x[2] - m) * inv), (__bf16)(__expf((float)x[3] - m) * inv) };
        *(bf16x4*)(Arow + (size_t)v * 4) = o;
    }
    for (int j = (nv << 2) + tid; j < limit; j += 256)
        Arow[j] = __float2bfloat16(__expf((float)Srow[j] - m) * inv);
    const __hip_bfloat16 z = __float2bfloat16(0.f);
    for (int j = limit + tid; j < zlimit; j += 256) Arow[j] = z;
}

// ---------------------------------------------------------------------------
// Row LayerNorm over 1024: writes f32 (always) + bf16 (optional)
// ---------------------------------------------------------------------------
__global__ __launch_bounds__(256) void layernorm_kernel(
    const float* __restrict__ X, const float* __restrict__ g, const float* __restrict__ b,
    float* __restrict__ outF, __hip_bfloat16* __restrict__ outB)
{
    __shared__ float sm[8];
    const int row = blockIdx.x;
    const int tid = threadIdx.x;
    const float4 v = ((const float4*)(X + (size_t)row * 1024))[tid];
    float s  = v.x + v.y + v.z + v.w;
    float ss = v.x * v.x + v.y * v.y + v.z * v.z + v.w * v.w;
#pragma unroll
    for (int o = 32; o; o >>= 1) { s += __shfl_down(s, o); ss += __shfl_down(ss, o); }
    if ((tid & 63) == 0) { sm[tid >> 6] = s; sm[4 + (tid >> 6)] = ss; }
    __syncthreads();
    s  = sm[0] + sm[1] + sm[2] + sm[3];
    ss = sm[4] + sm[5] + sm[6] + sm[7];
    const float mu   = s * (1.f / 1024.f);
    const float var  = ss * (1.f / 1024.f) - mu * mu;
    const float rstd = rsqrtf(var + 1e-5f);
    const float4 gv = ((const float4*)g)[tid];
    const float4 bv = ((const float4*)b)[tid];
    float4 o;
    o.x = (v.x - mu) * rstd * gv.x + bv.x;
    o.y = (v.y - mu) * rstd * gv.y + bv.y;
    o.z = (v.z - mu) * rstd * gv.z + bv.z;
    o.w = (v.w - mu) * rstd * gv.w + bv.w;
    ((float4*)(outF + (size_t)row * 1024))[tid] = o;
    if (outB) {
        bf16x4 ob = { (__bf16)o.x, (__bf16)o.y, (__bf16)o.z, (__bf16)o.w };
        *(bf16x4*)(outB + (size_t)row * 1024 + (size_t)tid * 4) = ob;
    }
}

// ---------------------------------------------------------------------------
// Launch
// ---------------------------------------------------------------------------
extern "C" void kernel_launch(void* const* d_in, const int* in_sizes, int n_in,
                              void* d_out, int out_size, void* d_ws, size_t ws_size,
                              hipStream_t stream)
{
    const int M = 4096, Pd = 1024, DFF = 4096, NS = 4096;
    const size_t MB = 1024 * 1024;

    const float* Y   = (const float*)d_in[0];
    const float* Xp  = (const float*)d_in[1];
    const float* wq1 = (const float*)d_in[2];  const float* bq1 = (const float*)d_in[3];
    const float* wk1 = (const float*)d_in[4];  const float* bk1 = (const float*)d_in[5];
    const float* wv1 = (const float*)d_in[6];  const float* bv1 = (const float*)d_in[7];
    const float* w0  = (const float*)d_in[8];  const float* b0  = (const float*)d_in[9];
    const float* g1  = (const float*)d_in[10]; const float* be1 = (const float*)d_in[11];
    const float* wq2 = (const float*)d_in[12]; const float* bq2 = (const float*)d_in[13];
    const float* wk2 = (const float*)d_in[14]; const float* bk2 = (const float*)d_in[15];
    const float* wv2 = (const float*)d_in[16]; const float* bv2 = (const float*)d_in[17];
    const float* w1  = (const float*)d_in[18]; const float* b1  = (const float*)d_in[19];
    const float* g2  = (const float*)d_in[20]; const float* be2 = (const float*)d_in[21];
    const float* w2  = (const float*)d_in[22]; const float* b2  = (const float*)d_in[23];
    const float* w3  = (const float*)d_in[24]; const float* b3  = (const float*)d_in[25];
    const float* g3  = (const float*)d_in[26]; const float* be3 = (const float*)d_in[27];

    // ---- workspace layout (MB offsets; lifetimes checked) ----
    char* ws = (char*)d_ws;
    __hip_bfloat16* Ybf   = (__hip_bfloat16*)(ws + 0 * MB);    // dead after QKV1 -> Ubf
    __hip_bfloat16* Ubf   = (__hip_bfloat16*)(ws + 0 * MB);
    __hip_bfloat16* Xpbf  = (__hip_bfloat16*)(ws + 8 * MB);    // dead after KV2 -> AVbf/Qbf
    __hip_bfloat16* AVbf  = (__hip_bfloat16*)(ws + 8 * MB);
    __hip_bfloat16* Qbf   = (__hip_bfloat16*)(ws + 8 * MB);
    __hip_bfloat16* wqkv1t= (__hip_bfloat16*)(ws + 16 * MB);   // [3072,1024]
    __hip_bfloat16* w0t   = (__hip_bfloat16*)(ws + 22 * MB);
    __hip_bfloat16* wq2t  = (__hip_bfloat16*)(ws + 24 * MB);
    __hip_bfloat16* wkv2t = (__hip_bfloat16*)(ws + 26 * MB);   // [2048,1024]
    __hip_bfloat16* w1t   = (__hip_bfloat16*)(ws + 30 * MB);
    __hip_bfloat16* w2t   = (__hip_bfloat16*)(ws + 32 * MB);   // [4096,1024]
    __hip_bfloat16* w3t   = (__hip_bfloat16*)(ws + 40 * MB);   // [1024,4096]
    float*          bqkv1 = (float*)(ws + 48 * MB);            // [3072]
    float*          bkv2  = (float*)(ws + 48 * MB + 512 * 1024);// [2048]
    __hip_bfloat16* QKV1  = (__hip_bfloat16*)(ws + 49 * MB);   // [4096,3072]
    __hip_bfloat16* KV2   = (__hip_bfloat16*)(ws + 73 * MB);   // [4096,2048]
    __hip_bfloat16* Vt    = (__hip_bfloat16*)(ws + 89 * MB);   // [1024,4096]
    __hip_bfloat16* Sb    = (__hip_bfloat16*)(ws + 97 * MB);   // [4096,4096] bf16 (32MB)
    __hip_bfloat16* Pb    = (__hip_bfloat16*)(ws + 97 * MB);   // splitK bf16 partials overlay
    __hip_bfloat16* Abf   = (__hip_bfloat16*)(ws + 161 * MB);  // [4096,4096] bf16 (32MB), also H
    float*          Xres  = (float*)(ws + 193 * MB);           // [4096,1024] f32
    float*          Uf    = (float*)(ws + 209 * MB);           // [4096,1024] f32
    float*          Out   = (float*)d_out;
    if (ws_size < 225 * MB) return;

    auto cvt = [&](const float* src, __hip_bfloat16* dst, int n) {
        convert_bf16_kernel<<<dim3(n / 1024), dim3(256), 0, stream>>>(src, dst, n / 4);
    };
    auto tconv = [&](const float* W, __hip_bfloat16* Wt, int K, int N) {
        transpose_convert_kernel<<<dim3(N / 32, K / 32), dim3(32, 8), 0, stream>>>(W, Wt, K, N);
    };
    auto tbf = [&](const __hip_bfloat16* src, int ls, __hip_bfloat16* dst, int ld, int R, int C) {
        transpose_bf16_kernel<<<dim3(C / 32, R / 32), dim3(32, 8), 0, stream>>>(src, ls, dst, ld);
    };
    auto gemm = [&](const __hip_bfloat16* A, int lda, const __hip_bfloat16* Bt, int ldb,
                    int Mm, int Nn, int Kk, int ldc,
                    const float* bias, int bmode, float scale, const float* res,
                    int relu, int causal, int trap, int ksplit,
                    float* Cf, __hip_bfloat16* Cb) {
        const int nz = ksplit ? (Kk + ksplit - 1) / ksplit : 1;
        gemm_bt<<<dim3(Nn / 128, Mm / 128, nz), dim3(256), 0, stream>>>(
            A, lda, Bt, ldb, Mm, Nn, Kk, ldc, bias, bmode, scale, res, relu, causal, trap, ksplit,
            Cf, Cb, 0, nullptr, nullptr, 0, 0, nullptr, nullptr);
    };
    auto reduce = [&](const __hip_bfloat16* P, int Mm, int Nn, int nsplit, int KC, int trapK,
                      const float* bias, const float* res, float* Cf, __hip_bfloat16* Cb) {
        reduce_k_kernel<<<dim3(Mm * Nn / 1024), dim3(256), 0, stream>>>(
            P, Mm, Nn, nsplit, KC, trapK, bias, res, Cf, Cb);
    };

    const float scl = 0.03125f;  // 1/sqrt(1024)

    // --- prep ---
    cvt(Y,  Ybf,  M * Pd);
    cvt(Xp, Xpbf, NS * Pd);
    tconv(wq1, wqkv1t,            Pd, Pd);
    tconv(wk1, wqkv1t + Pd * Pd,  Pd, Pd);
    tconv(wv1, wqkv1t + 2*Pd*Pd,  Pd, Pd);
    tconv(w0,  w0t,  Pd, Pd);
    tconv(wq2, wq2t, Pd, Pd);
    tconv(wk2, wkv2t,           Pd, Pd);
    tconv(wv2, wkv2t + Pd * Pd, Pd, Pd);
    tconv(w1,  w1t,  Pd, Pd);
    tconv(w2, w2t, Pd, DFF);
    tconv(w3, w3t, DFF, Pd);
    hipMemcpyAsync(bqkv1,            bq1, Pd * 4, hipMemcpyDeviceToDevice, stream);
    hipMemcpyAsync(bqkv1 + Pd,       bk1, Pd * 4, hipMemcpyDeviceToDevice, stream);
    hipMemcpyAsync(bqkv1 + 2 * Pd,   bv1, Pd * 4, hipMemcpyDeviceToDevice, stream);
    hipMemcpyAsync(bkv2,             bk2, Pd * 4, hipMemcpyDeviceToDevice, stream);
    hipMemcpyAsync(bkv2 + Pd,        bv2, Pd * 4, hipMemcpyDeviceToDevice, stream);

    // --- merged projections: QKV1 (24 n-blocks) + KV2 (16 n-blocks) ---
    gemm_bt<<<dim3(40, 32, 1), dim3(256), 0, stream>>>(
        Ybf, Pd, wqkv1t, Pd, M, 3072, Pd, 3072, bqkv1, 1, 1.f, nullptr, 0, 0, 0, 0,
        nullptr, QKV1,
        24, Xpbf, wkv2t, Pd, 2048, bkv2, KV2);

    // --- masked self-attention ---
    tbf(QKV1 + 2048, 3072, Vt, M, M, Pd);                       // V1 -> Vt [1024,4096]
    gemm(QKV1, 3072, QKV1 + 1024, 3072, M, M, Pd, M,
         nullptr, 0, scl, nullptr, 0, 1, 0, 0, nullptr, Sb);    // causal S (bf16)
    softmax_kernel<<<dim3(M), dim3(256), 0, stream>>>(Sb, Abf, M, 1);
    gemm(Abf, M, Vt, M, M, Pd, M, Pd,
         nullptr, 0, 1.f, nullptr, 0, 0, 1, 1024, nullptr, Pb); // AV1 splitK=4, trapezoid
    reduce(Pb, M, Pd, 4, 1024, M, nullptr, nullptr, nullptr, AVbf);
    gemm(AVbf, Pd, w0t, Pd, M, Pd, Pd, Pd,
         nullptr, 0, 1.f, nullptr, 0, 0, 0, 512, nullptr, Pb);  // w0 splitK=2
    reduce(Pb, M, Pd, 2, 512, 0, b0, Y, Xres, nullptr);
    layernorm_kernel<<<dim3(M), dim3(256), 0, stream>>>(Xres, g1, be1, Uf, Ubf);

    // --- cross-attention ---
    gemm(Ubf, Pd, wq2t, Pd, M, Pd, Pd, Pd,
         nullptr, 0, 1.f, nullptr, 0, 0, 0, 512, nullptr, Pb);  // wq2 splitK=2
    reduce(Pb, M, Pd, 2, 512, 0, bq2, nullptr, nullptr, Qbf);
    tbf(KV2 + 1024, 2048, Vt, NS, NS, Pd);                      // V2 -> Vt [1024,4096]
    gemm(Qbf, Pd, KV2, 2048, M, NS, Pd, NS,
         nullptr, 0, scl, nullptr, 0, 0, 0, 0, nullptr, Sb);    // S2 full (bf16)
    softmax_kernel<<<dim3(M), dim3(256), 0, stream>>>(Sb, Abf, NS, 0);
    gemm(Abf, NS, Vt, NS, M, Pd, NS, Pd,
         nullptr, 0, 1.f, nullptr, 0, 0, 0, 1024, nullptr, Pb); // AV2 splitK=4
    reduce(Pb, M, Pd, 4, 1024, 0, nullptr, nullptr, nullptr, AVbf);
    gemm(AVbf, Pd, w1t, Pd, M, Pd, Pd, Pd,
         nullptr, 0, 1.f, nullptr, 0, 0, 0, 512, nullptr, Pb);  // w1 splitK=2
    reduce(Pb, M, Pd, 2, 512, 0, b1, Uf, Xres, nullptr);
    layernorm_kernel<<<dim3(M), dim3(256), 0, stream>>>(Xres, g2, be2, Uf, Ubf);

    // --- FFN ---
    gemm(Ubf, Pd, w2t, Pd, M, DFF, Pd, DFF, b2, 1, 1.f, nullptr, 1, 0, 0, 0, nullptr, Abf);
    gemm(Abf, DFF, w3t, DFF, M, Pd, DFF, Pd,
         nullptr, 0, 1.f, nullptr, 0, 0, 0, 1024, nullptr, Pb); // FFN2 splitK=4
    reduce(Pb, M, Pd, 4, 1024, 0, b3, Uf, Xres, nullptr);
    layernorm_kernel<<<dim3(M), dim3(256), 0, stream>>>(Xres, g3, be3, Out, nullptr);
}

// Round 8
// 751.225 us; speedup vs baseline: 1.0817x; 1.0356x over previous
//
#include <hip/hip_runtime.h>
#include <hip/hip_bf16.h>

typedef __bf16 bf16x8 __attribute__((ext_vector_type(8)));
typedef __bf16 bf16x4 __attribute__((ext_vector_type(4)));
typedef float f32x4 __attribute__((ext_vector_type(4)));

#define AS1P(p) ((__attribute__((address_space(1))) void*)(void*)(p))
#define AS3P(p) ((__attribute__((address_space(3))) void*)(p))

// ---------------------------------------------------------------------------
// 128x128 bf16 GEMM (projections / thin-N): BK=32 triple-buffer, depth-2
// prefetch, single-barrier K-loop, XOR-swizzled LDS (conflict-free), XCD
// region swizzle. Per iter: [vmcnt(4) -> s_barrier -> issue k+2 -> 16 mfma].
// ---------------------------------------------------------------------------
__global__ __launch_bounds__(256, 3) void gemm_bt(
    const __hip_bfloat16* __restrict__ A, int lda,
    const __hip_bfloat16* __restrict__ Bt, int ldb,
    int M, int N, int K, int ldc,
    const float* __restrict__ bias, int bias_mode,   // 0 none, 1 per-col, 2 per-row
    float scale,
    const float* __restrict__ residual,              // f32 [M,ldc] or null
    int relu, int causal_skip, int trapezoid, int ksplit,
    float* __restrict__ Cf, __hip_bfloat16* __restrict__ Cb,
    // fused second GEMM (blocks with nb >= nsplit1); shares lda/M/K
    int nsplit1, const __hip_bfloat16* __restrict__ A2,
    const __hip_bfloat16* __restrict__ Bt2, int ldb2, int ldc2,
    const float* __restrict__ bias2, __hip_bfloat16* __restrict__ Cb2)
{
    int nb = blockIdx.x;
    int mb = blockIdx.y;
    {   // XCD-aware 2D-region swizzle (identity if shape not divisible)
        const int gx = gridDim.x, gy = gridDim.y;
        if ((gx & 3) == 0 && (gy & 1) == 0) {
            const int id = mb * gx + nb;
            const int X  = id & 7;
            const int L  = id >> 3;
            const int rn = gx >> 2, rm = gy >> 1;
            const int nb_l = L / rm, mb_l = L - nb_l * rm;
            nb = (X & 3) * rn + nb_l;
            mb = (X >> 2) * rm + mb_l;
        }
    }
    if (nsplit1 && nb >= nsplit1) {
        A = A2; Bt = Bt2; ldb = ldb2; ldc = ldc2; bias = bias2;
        Cb = Cb2; Cf = nullptr; residual = nullptr;
        nb -= nsplit1;
    }
    const int m_base = mb * 128;
    const int n_base = nb * 128;
    if (causal_skip && (n_base > m_base + 127)) return;
    int Kend = K;
    if (trapezoid) { int kl = m_base + 128; Kend = kl < K ? kl : K; }
    int kb = 0, ke = Kend;
    if (ksplit) {
        kb = blockIdx.z * ksplit;
        int k2 = kb + ksplit; ke = k2 < Kend ? k2 : Kend;
        if (kb >= ke) return;
        Cb += (size_t)blockIdx.z * M * ldc;
        Cf = nullptr;
    }
    const int nt = (ke - kb) >> 5;

    __shared__ __align__(16) __hip_bfloat16 Lds[3][8192];

    const int tid  = threadIdx.x;
    const int lane = tid & 63;
    const int wave = tid >> 6;
    const int wm = (wave >> 1) * 64;
    const int wn = (wave & 1) * 64;

    f32x4 acc[4][4];
#pragma unroll
    for (int i = 0; i < 4; ++i)
#pragma unroll
        for (int j = 0; j < 4; ++j) acc[i][j] = f32x4{0.f, 0.f, 0.f, 0.f};

    const bool isA = wave < 2;
    const __hip_bfloat16* G = isA ? (A + (size_t)m_base * lda) : (Bt + (size_t)n_base * ldb);
    const int ldg = isA ? lda : ldb;
    const int q0 = (wave & 1) * 4;
    const int rsub = lane >> 2;
    const int cx   = (lane & 3) ^ ((lane >> 3) & 3);
    const size_t grow = (size_t)(q0 * 16 + rsub) * ldg + (size_t)cx * 8 + kb;
    const int ldsoff = (isA ? 0 : 4096) + q0 * 512;

    const int lrow = lane & 15;
    const int cph  = ((lane >> 4) ^ ((lrow >> 1) & 3)) * 8;

#define ISSUE_TILE(KT, STG)                                                      \
    {                                                                            \
        const __hip_bfloat16* g = G + grow + (size_t)(KT) * 32;                  \
        __hip_bfloat16* dst = &Lds[STG][ldsoff];                                 \
        _Pragma("unroll")                                                        \
        for (int q = 0; q < 4; ++q) {                                            \
            __builtin_amdgcn_global_load_lds(AS1P(g), AS3P(dst), 16, 0, 0);      \
            g += (size_t)16 * ldg; dst += 512;                                   \
        }                                                                        \
    }

    ISSUE_TILE(0, 0)
    if (nt > 1) ISSUE_TILE(1, 1)

    int cur = 0;
    for (int kt = 0; kt < nt; ++kt) {
        __builtin_amdgcn_sched_barrier(0);
        if (kt + 1 < nt) __builtin_amdgcn_s_waitcnt(0x0F74);  // vmcnt(4)
        else             __builtin_amdgcn_s_waitcnt(0x0F70);  // vmcnt(0)
        __builtin_amdgcn_sched_barrier(0);
        __builtin_amdgcn_s_barrier();
        __builtin_amdgcn_sched_barrier(0);
        if (kt + 2 < nt) {
            int s2 = cur + 2; if (s2 >= 3) s2 -= 3;
            ISSUE_TILE(kt + 2, s2)
        }

        bf16x8 af[4], bfv[4];
#pragma unroll
        for (int i = 0; i < 4; ++i)
            af[i] = *(const bf16x8*)&Lds[cur][(wm + i * 16 + lrow) * 32 + cph];
#pragma unroll
        for (int j = 0; j < 4; ++j)
            bfv[j] = *(const bf16x8*)&Lds[cur][4096 + (wn + j * 16 + lrow) * 32 + cph];
#pragma unroll
        for (int i = 0; i < 4; ++i)
#pragma unroll
            for (int j = 0; j < 4; ++j)
                acc[i][j] = __builtin_amdgcn_mfma_f32_16x16x32_bf16(af[i], bfv[j], acc[i][j], 0, 0, 0);

        cur = (cur + 1 == 3) ? 0 : cur + 1;
    }
#undef ISSUE_TILE

    const int r0 = (lane >> 4) * 4;
    const int c0 = lane & 15;
#pragma unroll
    for (int i = 0; i < 4; ++i) {
#pragma unroll
        for (int j = 0; j < 4; ++j) {
            const int col = n_base + wn + j * 16 + c0;
#pragma unroll
            for (int r = 0; r < 4; ++r) {
                const int row = m_base + wm + i * 16 + r0 + r;
                float v = acc[i][j][r] * scale;
                if (bias_mode == 1) v += bias[col];
                else if (bias_mode == 2) v += bias[row];
                if (relu) v = fmaxf(v, 0.f);
                const size_t idx = (size_t)row * ldc + col;
                if (residual) v += residual[idx];
                if (Cf) Cf[idx] = v;
                else    Cb[idx] = __float2bfloat16(v);
            }
        }
    }
}

// ---------------------------------------------------------------------------
// 256x128 bf16 GEMM (big shapes): 4 waves each 128x64 (8x4 mfma tiles),
// BK=32 triple-buffer (72KB LDS, 2 blocks/CU), depth-2 prefetch, single
// barrier per iter. 32 MFMA per wave per barrier: 2x the FLOP amortizing
// the same per-iteration overhead as the 128x128 kernel.
// Staging per wave: 4 A-issues (rows wave*64+q*16) + 2 B-issues
// (rows wave*32+q*16) = 6 DMA/iter -> vmcnt(6) drains the current tile.
// ---------------------------------------------------------------------------
__global__ __launch_bounds__(256, 2) void gemm_bt2(
    const __hip_bfloat16* __restrict__ A, int lda,
    const __hip_bfloat16* __restrict__ Bt, int ldb,
    int M, int N, int K, int ldc,
    const float* __restrict__ bias, int bias_mode,
    float scale,
    int relu, int causal_skip, int trapezoid, int ksplit,
    __hip_bfloat16* __restrict__ Cb)
{
    int nb = blockIdx.x;
    int mb = blockIdx.y;
    {   // XCD-aware 2D-region swizzle
        const int gx = gridDim.x, gy = gridDim.y;
        if ((gx & 3) == 0 && (gy & 1) == 0) {
            const int id = mb * gx + nb;
            const int X  = id & 7;
            const int L  = id >> 3;
            const int rn = gx >> 2, rm = gy >> 1;
            const int nb_l = L / rm, mb_l = L - nb_l * rm;
            nb = (X & 3) * rn + nb_l;
            mb = (X >> 2) * rm + mb_l;
        }
    }
    const int m_base = mb * 256;
    const int n_base = nb * 128;
    if (causal_skip && (n_base > m_base + 255)) return;
    int Kend = K;
    if (trapezoid) { int kl = m_base + 256; Kend = kl < K ? kl : K; }
    int kb = 0, ke = Kend;
    if (ksplit) {
        kb = blockIdx.z * ksplit;
        int k2 = kb + ksplit; ke = k2 < Kend ? k2 : Kend;
        if (kb >= ke) return;
        Cb += (size_t)blockIdx.z * M * ldc;
    }
    const int nt = (ke - kb) >> 5;

    // [stage][ A 256x32 (8192 elems) | B 128x32 (4096 elems) ] = 3 x 24 KB
    __shared__ __align__(16) __hip_bfloat16 Lds[3][12288];

    const int tid  = threadIdx.x;
    const int lane = tid & 63;
    const int wave = tid >> 6;
    const int wm = wave * 64;          // NOTE: wave covers A rows [wm*? ] — see below
    // wave tile: rows [ (wave>>1)*128 , +128 ), cols [ (wave&1)*64, +64 )
    const int wtm = (wave >> 1) * 128;
    const int wtn = (wave & 1) * 64;

    f32x4 acc[8][4];
#pragma unroll
    for (int i = 0; i < 8; ++i)
#pragma unroll
        for (int j = 0; j < 4; ++j) acc[i][j] = f32x4{0.f, 0.f, 0.f, 0.f};

    // staging: wave w -> A rows [w*64, w*64+64) (4 issues) + B rows [w*32, w*32+32) (2 issues)
    const int rsub = lane >> 2;                         // row within issue (0..15)
    const int cx   = (lane & 3) ^ ((lane >> 3) & 3);    // swizzled source chunk
    const __hip_bfloat16* GA = A  + (size_t)(m_base + wave * 64) * lda + (size_t)rsub * lda + (size_t)cx * 8 + kb;
    const __hip_bfloat16* GB = Bt + (size_t)(n_base + wave * 32) * ldb + (size_t)rsub * ldb + (size_t)cx * 8 + kb;
    const int ldsA = wave * 2048;                       // elems
    const int ldsB = 8192 + wave * 1024;

    const int lrow = lane & 15;
    const int cph  = ((lane >> 4) ^ ((lrow >> 1) & 3)) * 8;

#define ISSUE_TILE2(KT, STG)                                                     \
    {                                                                            \
        const size_t ko = (size_t)(KT) * 32;                                     \
        const __hip_bfloat16* ga = GA + ko;                                      \
        __hip_bfloat16* da = &Lds[STG][ldsA];                                    \
        _Pragma("unroll")                                                        \
        for (int q = 0; q < 4; ++q) {                                            \
            __builtin_amdgcn_global_load_lds(AS1P(ga), AS3P(da), 16, 0, 0);      \
            ga += (size_t)16 * lda; da += 512;                                   \
        }                                                                        \
        const __hip_bfloat16* gb = GB + ko;                                      \
        __hip_bfloat16* db = &Lds[STG][ldsB];                                    \
        _Pragma("unroll")                                                        \
        for (int q = 0; q < 2; ++q) {                                            \
            __builtin_amdgcn_global_load_lds(AS1P(gb), AS3P(db), 16, 0, 0);      \
            gb += (size_t)16 * ldb; db += 512;                                   \
        }                                                                        \
    }

    ISSUE_TILE2(0, 0)
    if (nt > 1) ISSUE_TILE2(1, 1)

    int cur = 0;
    for (int kt = 0; kt < nt; ++kt) {
        __builtin_amdgcn_sched_barrier(0);
        if (kt + 1 < nt) __builtin_amdgcn_s_waitcnt(0x0F76);  // vmcnt(6): tile kt drained
        else             __builtin_amdgcn_s_waitcnt(0x0F70);  // vmcnt(0)
        __builtin_amdgcn_sched_barrier(0);
        __builtin_amdgcn_s_barrier();
        __builtin_amdgcn_sched_barrier(0);
        if (kt + 2 < nt) {
            int s2 = cur + 2; if (s2 >= 3) s2 -= 3;
            ISSUE_TILE2(kt + 2, s2)
        }

        bf16x8 af[8], bfv[4];
#pragma unroll
        for (int i = 0; i < 8; ++i)
            af[i] = *(const bf16x8*)&Lds[cur][(wtm + i * 16 + lrow) * 32 + cph];
#pragma unroll
        for (int j = 0; j < 4; ++j)
            bfv[j] = *(const bf16x8*)&Lds[cur][8192 + (wtn + j * 16 + lrow) * 32 + cph];
#pragma unroll
        for (int i = 0; i < 8; ++i)
#pragma unroll
            for (int j = 0; j < 4; ++j)
                acc[i][j] = __builtin_amdgcn_mfma_f32_16x16x32_bf16(af[i], bfv[j], acc[i][j], 0, 0, 0);

        cur = (cur + 1 == 3) ? 0 : cur + 1;
    }
#undef ISSUE_TILE2

    const int r0 = (lane >> 4) * 4;
    const int c0 = lane & 15;
#pragma unroll
    for (int i = 0; i < 8; ++i) {
#pragma unroll
        for (int j = 0; j < 4; ++j) {
            const int col = n_base + wtn + j * 16 + c0;
#pragma unroll
            for (int r = 0; r < 4; ++r) {
                const int row = m_base + wtm + i * 16 + r0 + r;
                float v = acc[i][j][r] * scale;
                if (bias_mode == 1) v += bias[col];
                else if (bias_mode == 2) v += bias[row];
                if (relu) v = fmaxf(v, 0.f);
                Cb[(size_t)row * ldc + col] = __float2bfloat16(v);
            }
        }
    }
}

// ---------------------------------------------------------------------------
// Split-K reducer over bf16 partials: C = epi( sum_z Pb[z] )
// ---------------------------------------------------------------------------
__global__ __launch_bounds__(256) void reduce_k_kernel(
    const __hip_bfloat16* __restrict__ Pb, int M, int N, int nsplit, int KC, int trapK,
    const float* __restrict__ bias, const float* __restrict__ residual,
    float* __restrict__ Cf, __hip_bfloat16* __restrict__ Cb)
{
    const int idx = blockIdx.x * 256 + threadIdx.x;
    const int nv = N >> 2;
    const int row = idx / nv;
    if (row >= M) return;
    const int c4 = (idx - row * nv) * 4;
    int nc = nsplit;
    if (trapK) {
        int kend = (row & ~255) + 256; if (kend > trapK) kend = trapK;
        nc = (kend + KC - 1) / KC;
    }
    float s0 = 0.f, s1 = 0.f, s2 = 0.f, s3 = 0.f;
    for (int c = 0; c < nc; ++c) {
        const bf16x4 p = *(const bf16x4*)(Pb + ((size_t)c * M + row) * N + c4);
        s0 += (float)p[0]; s1 += (float)p[1]; s2 += (float)p[2]; s3 += (float)p[3];
    }
    if (bias) {
        const f32x4 b = *(const f32x4*)(bias + c4);
        s0 += b[0]; s1 += b[1]; s2 += b[2]; s3 += b[3];
    }
    if (residual) {
        const f32x4 rv = *(const f32x4*)(residual + (size_t)row * N + c4);
        s0 += rv[0]; s1 += rv[1]; s2 += rv[2]; s3 += rv[3];
    }
    if (Cf) { f32x4 o = {s0, s1, s2, s3}; *(f32x4*)(Cf + (size_t)row * N + c4) = o; }
    else {
        bf16x4 o = { (__bf16)s0, (__bf16)s1, (__bf16)s2, (__bf16)s3 };
        *(bf16x4*)(Cb + (size_t)row * N + c4) = o;
    }
}

// ---------------------------------------------------------------------------
// f32 -> bf16 convert (4 elems/thread)
// ---------------------------------------------------------------------------
__global__ __launch_bounds__(256) void convert_bf16_kernel(
    const float* __restrict__ x, __hip_bfloat16* __restrict__ y, int n4)
{
    const int i = blockIdx.x * 256 + threadIdx.x;
    if (i >= n4) return;
    const float4 v = ((const float4*)x)[i];
    bf16x4 o = { (__bf16)v.x, (__bf16)v.y, (__bf16)v.z, (__bf16)v.w };
    *(bf16x4*)(y + (size_t)i * 4) = o;
}

// ---------------------------------------------------------------------------
// W[K,N] f32  ->  Wt[N,K] bf16   (32x32 LDS tile, padded)
// ---------------------------------------------------------------------------
__global__ __launch_bounds__(256) void transpose_convert_kernel(
    const float* __restrict__ W, __hip_bfloat16* __restrict__ Wt, int K, int N)
{
    __shared__ float t[32][33];
    const int k0 = blockIdx.y * 32;
    const int n0 = blockIdx.x * 32;
    const int tx = threadIdx.x;
    for (int i = threadIdx.y; i < 32; i += 8)
        t[i][tx] = W[(size_t)(k0 + i) * N + n0 + tx];
    __syncthreads();
    for (int i = threadIdx.y; i < 32; i += 8)
        Wt[(size_t)(n0 + i) * K + k0 + tx] = __float2bfloat16(t[tx][i]);
}

// ---------------------------------------------------------------------------
// bf16 transpose: dst[c][r] = src[r][c]
// ---------------------------------------------------------------------------
__global__ __launch_bounds__(256) void transpose_bf16_kernel(
    const __hip_bfloat16* __restrict__ src, int ls,
    __hip_bfloat16* __restrict__ dst, int ld)
{
    __shared__ __hip_bfloat16 t[32][33];
    const int r0 = blockIdx.y * 32;
    const int c0 = blockIdx.x * 32;
    const int tx = threadIdx.x;
    for (int i = threadIdx.y; i < 32; i += 8)
        t[i][tx] = src[(size_t)(r0 + i) * ls + c0 + tx];
    __syncthreads();
    for (int i = threadIdx.y; i < 32; i += 8)
        dst[(size_t)(c0 + i) * ld + r0 + tx] = t[tx][i];
}

// ---------------------------------------------------------------------------
// Row softmax over bf16 S: causal masks j>row; zero-fill to the 256-row
// trapezoid boundary (the 256-tile AV GEMM reads that far).
// ---------------------------------------------------------------------------
__global__ __launch_bounds__(256) void softmax_kernel(
    const __hip_bfloat16* __restrict__ S, __hip_bfloat16* __restrict__ A, int N, int causal)
{
    __shared__ float sm[4];
    const int row = blockIdx.x;
    const int tid = threadIdx.x;
    const int limit = causal ? (row + 1) : N;
    const int zlimit = causal ? (((row & ~255) + 256) < N ? ((row & ~255) + 256) : N) : N;
    const __hip_bfloat16* Srow = S + (size_t)row * N;
    __hip_bfloat16* Arow = A + (size_t)row * N;
    const int nv = limit >> 2;

    float m = -3.0e38f;
    for (int v = tid; v < nv; v += 256) {
        const bf16x4 x = *(const bf16x4*)(Srow + (size_t)v * 4);
        m = fmaxf(m, fmaxf(fmaxf((float)x[0], (float)x[1]), fmaxf((float)x[2], (float)x[3])));
    }
    for (int j = (nv << 2) + tid; j < limit; j += 256) m = fmaxf(m, (float)Srow[j]);
#pragma unroll
    for (int o = 32; o; o >>= 1) m = fmaxf(m, __shfl_down(m, o));
    if ((tid & 63) == 0) sm[tid >> 6] = m;
    __syncthreads();
    m = fmaxf(fmaxf(sm[0], sm[1]), fmaxf(sm[2], sm[3]));
    __syncthreads();

    float s = 0.f;
    for (int v = tid; v < nv; v += 256) {
        const bf16x4 x = *(const bf16x4*)(Srow + (size_t)v * 4);
        s += __expf((float)x[0] - m) + __expf((float)x[1] - m)
           + __expf((float)x[2] - m) + __expf((float)x[3] - m);
    }
    for (int j = (nv << 2) + tid; j < limit; j += 256) s += __expf((float)Srow[j] - m);
#pragma unroll
    for (int o = 32; o; o >>= 1) s += __shfl_down(s, o);
    if ((tid & 63) == 0) sm[tid >> 6] = s;
    __syncthreads();
    s = sm[0] + sm[1] + sm[2] + sm[3];
    const float inv = 1.f / s;

    for (int v = tid; v < nv; v += 256) {
        const bf16x4 x = *(const bf16x4*)(Srow + (size_t)v * 4);
        bf16x4 o = { (__bf16)(__expf((float)x[0] - m) * inv), (__bf16)(__expf((float)x[1] - m) * inv),
                     (__bf16)(__expf((float)x[2] - m) * inv), (__bf16)(__expf((float)x[3] - m) * inv) };
        *(bf16x4*)(Arow + (size_t)v * 4) = o;
    }
    for (int j = (nv << 2) + tid; j < limit; j += 256)
        Arow[j] = __float2bfloat16(__expf((float)Srow[j] - m) * inv);
    const __hip_bfloat16 z = __float2bfloat16(0.f);
    for (int j = limit + tid; j < zlimit; j += 256) Arow[j] = z;
}

// ---------------------------------------------------------------------------
// Row LayerNorm over 1024: writes f32 (always) + bf16 (optional)
// ---------------------------------------------------------------------------
__global__ __launch_bounds__(256) void layernorm_kernel(
    const float* __restrict__ X, const float* __restrict__ g, const float* __restrict__ b,
    float* __restrict__ outF, __hip_bfloat16* __restrict__ outB)
{
    __shared__ float sm[8];
    const int row = blockIdx.x;
    const int tid = threadIdx.x;
    const float4 v = ((const float4*)(X + (size_t)row * 1024))[tid];
    float s  = v.x + v.y + v.z + v.w;
    float ss = v.x * v.x + v.y * v.y + v.z * v.z + v.w * v.w;
#pragma unroll
    for (int o = 32; o; o >>= 1) { s += __shfl_down(s, o); ss += __shfl_down(ss, o); }
    if ((tid & 63) == 0) { sm[tid >> 6] = s; sm[4 + (tid >> 6)] = ss; }
    __syncthreads();
    s  = sm[0] + sm[1] + sm[2] + sm[3];
    ss = sm[4] + sm[5] + sm[6] + sm[7];
    const float mu   = s * (1.f / 1024.f);
    const float var  = ss * (1.f / 1024.f) - mu * mu;
    const float rstd = rsqrtf(var + 1e-5f);
    const float4 gv = ((const float4*)g)[tid];
    const float4 bv = ((const float4*)b)[tid];
    float4 o;
    o.x = (v.x - mu) * rstd * gv.x + bv.x;
    o.y = (v.y - mu) * rstd * gv.y + bv.y;
    o.z = (v.z - mu) * rstd * gv.z + bv.z;
    o.w = (v.w - mu) * rstd * gv.w + bv.w;
    ((float4*)(outF + (size_t)row * 1024))[tid] = o;
    if (outB) {
        bf16x4 ob = { (__bf16)o.x, (__bf16)o.y, (__bf16)o.z, (__bf16)o.w };
        *(bf16x4*)(outB + (size_t)row * 1024 + (size_t)tid * 4) = ob;
    }
}

// ---------------------------------------------------------------------------
// Launch
// ---------------------------------------------------------------------------
extern "C" void kernel_launch(void* const* d_in, const int* in_sizes, int n_in,
                              void* d_out, int out_size, void* d_ws, size_t ws_size,
                              hipStream_t stream)
{
    const int M = 4096, Pd = 1024, DFF = 4096, NS = 4096;
    const size_t MB = 1024 * 1024;

    const float* Y   = (const float*)d_in[0];
    const float* Xp  = (const float*)d_in[1];
    const float* wq1 = (const float*)d_in[2];  const float* bq1 = (const float*)d_in[3];
    const float* wk1 = (const float*)d_in[4];  const float* bk1 = (const float*)d_in[5];
    const float* wv1 = (const float*)d_in[6];  const float* bv1 = (const float*)d_in[7];
    const float* w0  = (const float*)d_in[8];  const float* b0  = (const float*)d_in[9];
    const float* g1  = (const float*)d_in[10]; const float* be1 = (const float*)d_in[11];
    const float* wq2 = (const float*)d_in[12]; const float* bq2 = (const float*)d_in[13];
    const float* wk2 = (const float*)d_in[14]; const float* bk2 = (const float*)d_in[15];
    const float* wv2 = (const float*)d_in[16]; const float* bv2 = (const float*)d_in[17];
    const float* w1  = (const float*)d_in[18]; const float* b1  = (const float*)d_in[19];
    const float* g2  = (const float*)d_in[20]; const float* be2 = (const float*)d_in[21];
    const float* w2  = (const float*)d_in[22]; const float* b2  = (const float*)d_in[23];
    const float* w3  = (const float*)d_in[24]; const float* b3  = (const float*)d_in[25];
    const float* g3  = (const float*)d_in[26]; const float* be3 = (const float*)d_in[27];

    // ---- workspace layout ----
    char* ws = (char*)d_ws;
    __hip_bfloat16* Ybf   = (__hip_bfloat16*)(ws + 0 * MB);
    __hip_bfloat16* Ubf   = (__hip_bfloat16*)(ws + 0 * MB);
    __hip_bfloat16* Xpbf  = (__hip_bfloat16*)(ws + 8 * MB);
    __hip_bfloat16* AVbf  = (__hip_bfloat16*)(ws + 8 * MB);
    __hip_bfloat16* Qbf   = (__hip_bfloat16*)(ws + 8 * MB);
    __hip_bfloat16* wqkv1t= (__hip_bfloat16*)(ws + 16 * MB);
    __hip_bfloat16* w0t   = (__hip_bfloat16*)(ws + 22 * MB);
    __hip_bfloat16* wq2t  = (__hip_bfloat16*)(ws + 24 * MB);
    __hip_bfloat16* wkv2t = (__hip_bfloat16*)(ws + 26 * MB);
    __hip_bfloat16* w1t   = (__hip_bfloat16*)(ws + 30 * MB);
    __hip_bfloat16* w2t   = (__hip_bfloat16*)(ws + 32 * MB);
    __hip_bfloat16* w3t   = (__hip_bfloat16*)(ws + 40 * MB);
    float*          bqkv1 = (float*)(ws + 48 * MB);
    float*          bkv2  = (float*)(ws + 48 * MB + 512 * 1024);
    __hip_bfloat16* QKV1  = (__hip_bfloat16*)(ws + 49 * MB);
    __hip_bfloat16* KV2   = (__hip_bfloat16*)(ws + 73 * MB);
    __hip_bfloat16* Vt    = (__hip_bfloat16*)(ws + 89 * MB);
    __hip_bfloat16* Sb    = (__hip_bfloat16*)(ws + 97 * MB);
    __hip_bfloat16* Pb    = (__hip_bfloat16*)(ws + 97 * MB);
    __hip_bfloat16* Abf   = (__hip_bfloat16*)(ws + 161 * MB);
    float*          Xres  = (float*)(ws + 193 * MB);
    float*          Uf    = (float*)(ws + 209 * MB);
    float*          Out   = (float*)d_out;
    if (ws_size < 225 * MB) return;

    auto cvt = [&](const float* src, __hip_bfloat16* dst, int n) {
        convert_bf16_kernel<<<dim3(n / 1024), dim3(256), 0, stream>>>(src, dst, n / 4);
    };
    auto tconv = [&](const float* W, __hip_bfloat16* Wt, int K, int N) {
        transpose_convert_kernel<<<dim3(N / 32, K / 32), dim3(32, 8), 0, stream>>>(W, Wt, K, N);
    };
    auto tbf = [&](const __hip_bfloat16* src, int ls, __hip_bfloat16* dst, int ld, int R, int C) {
        transpose_bf16_kernel<<<dim3(C / 32, R / 32), dim3(32, 8), 0, stream>>>(src, ls, dst, ld);
    };
    auto gemm = [&](const __hip_bfloat16* A, int lda, const __hip_bfloat16* Bt, int ldb,
                    int Mm, int Nn, int Kk, int ldc,
                    const float* bias, int bmode, float scale, const float* res,
                    int relu, int causal, int trap, int ksplit,
                    float* Cf, __hip_bfloat16* Cb) {
        const int nz = ksplit ? (Kk + ksplit - 1) / ksplit : 1;
        gemm_bt<<<dim3(Nn / 128, Mm / 128, nz), dim3(256), 0, stream>>>(
            A, lda, Bt, ldb, Mm, Nn, Kk, ldc, bias, bmode, scale, res, relu, causal, trap, ksplit,
            Cf, Cb, 0, nullptr, nullptr, 0, 0, nullptr, nullptr);
    };
    auto gemm2 = [&](const __hip_bfloat16* A, int lda, const __hip_bfloat16* Bt, int ldb,
                     int Mm, int Nn, int Kk, int ldc,
                     const float* bias, int bmode, float scale,
                     int relu, int causal, int trap, int ksplit, __hip_bfloat16* Cb) {
        const int nz = ksplit ? (Kk + ksplit - 1) / ksplit : 1;
        gemm_bt2<<<dim3(Nn / 128, Mm / 256, nz), dim3(256), 0, stream>>>(
            A, lda, Bt, ldb, Mm, Nn, Kk, ldc, bias, bmode, scale, relu, causal, trap, ksplit, Cb);
    };
    auto reduce = [&](const __hip_bfloat16* P, int Mm, int Nn, int nsplit, int KC, int trapK,
                      const float* bias, const float* res, float* Cf, __hip_bfloat16* Cb) {
        reduce_k_kernel<<<dim3(Mm * Nn / 1024), dim3(256), 0, stream>>>(
            P, Mm, Nn, nsplit, KC, trapK, bias, res, Cf, Cb);
    };

    const float scl = 0.03125f;  // 1/sqrt(1024)

    // --- prep ---
    cvt(Y,  Ybf,  M * Pd);
    cvt(Xp, Xpbf, NS * Pd);
    tconv(wq1, wqkv1t,            Pd, Pd);
    tconv(wk1, wqkv1t + Pd * Pd,  Pd, Pd);
    tconv(wv1, wqkv1t + 2*Pd*Pd,  Pd, Pd);
    tconv(w0,  w0t,  Pd, Pd);
    tconv(wq2, wq2t, Pd, Pd);
    tconv(wk2, wkv2t,           Pd, Pd);
    tconv(wv2, wkv2t + Pd * Pd, Pd, Pd);
    tconv(w1,  w1t,  Pd, Pd);
    tconv(w2, w2t, Pd, DFF);
    tconv(w3, w3t, DFF, Pd);
    hipMemcpyAsync(bqkv1,            bq1, Pd * 4, hipMemcpyDeviceToDevice, stream);
    hipMemcpyAsync(bqkv1 + Pd,       bk1, Pd * 4, hipMemcpyDeviceToDevice, stream);
    hipMemcpyAsync(bqkv1 + 2 * Pd,   bv1, Pd * 4, hipMemcpyDeviceToDevice, stream);
    hipMemcpyAsync(bkv2,             bk2, Pd * 4, hipMemcpyDeviceToDevice, stream);
    hipMemcpyAsync(bkv2 + Pd,        bv2, Pd * 4, hipMemcpyDeviceToDevice, stream);

    // --- merged projections: QKV1 (24 n-blocks) + KV2 (16 n-blocks) ---
    gemm_bt<<<dim3(40, 32, 1), dim3(256), 0, stream>>>(
        Ybf, Pd, wqkv1t, Pd, M, 3072, Pd, 3072, bqkv1, 1, 1.f, nullptr, 0, 0, 0, 0,
        nullptr, QKV1,
        24, Xpbf, wkv2t, Pd, 2048, bkv2, KV2);

    // --- masked self-attention ---
    tbf(QKV1 + 2048, 3072, Vt, M, M, Pd);                        // V1 -> Vt [1024,4096]
    gemm2(QKV1, 3072, QKV1 + 1024, 3072, M, M, Pd, M,
          nullptr, 0, scl, 0, 1, 0, 0, Sb);                      // causal S (256-tile)
    softmax_kernel<<<dim3(M), dim3(256), 0, stream>>>(Sb, Abf, M, 1);
    gemm2(Abf, M, Vt, M, M, Pd, M, Pd,
          nullptr, 0, 1.f, 0, 0, 1, 1024, Pb);                   // AV1 trapezoid splitK=4
    reduce(Pb, M, Pd, 4, 1024, M, nullptr, nullptr, nullptr, AVbf);
    gemm(AVbf, Pd, w0t, Pd, M, Pd, Pd, Pd,
         nullptr, 0, 1.f, nullptr, 0, 0, 0, 512, nullptr, Pb);   // w0 splitK=2
    reduce(Pb, M, Pd, 2, 512, 0, b0, Y, Xres, nullptr);
    layernorm_kernel<<<dim3(M), dim3(256), 0, stream>>>(Xres, g1, be1, Uf, Ubf);

    // --- cross-attention ---
    gemm(Ubf, Pd, wq2t, Pd, M, Pd, Pd, Pd,
         nullptr, 0, 1.f, nullptr, 0, 0, 0, 512, nullptr, Pb);   // wq2 splitK=2
    reduce(Pb, M, Pd, 2, 512, 0, bq2, nullptr, nullptr, Qbf);
    tbf(KV2 + 1024, 2048, Vt, NS, NS, Pd);                       // V2 -> Vt [1024,4096]
    gemm2(Qbf, Pd, KV2, 2048, M, NS, Pd, NS,
          nullptr, 0, scl, 0, 0, 0, 0, Sb);                      // S2 (256-tile)
    softmax_kernel<<<dim3(M), dim3(256), 0, stream>>>(Sb, Abf, NS, 0);
    gemm2(Abf, NS, Vt, NS, M, Pd, NS, Pd,
          nullptr, 0, 1.f, 0, 0, 0, 1024, Pb);                   // AV2 splitK=4
    reduce(Pb, M, Pd, 4, 1024, 0, nullptr, nullptr, nullptr, AVbf);
    gemm(AVbf, Pd, w1t, Pd, M, Pd, Pd, Pd,
         nullptr, 0, 1.f, nullptr, 0, 0, 0, 512, nullptr, Pb);   // w1 splitK=2
    reduce(Pb, M, Pd, 2, 512, 0, b1, Uf, Xres, nullptr);
    layernorm_kernel<<<dim3(M), dim3(256), 0, stream>>>(Xres, g2, be2, Uf, Ubf);

    // --- FFN ---
    gemm2(Ubf, Pd, w2t, Pd, M, DFF, Pd, DFF, b2, 1, 1.f, 1, 0, 0, 0, Abf);  // FFN1 relu
    gemm2(Abf, DFF, w3t, DFF, M, Pd, DFF, Pd,
          nullptr, 0, 1.f, 0, 0, 0, 1024, Pb);                   // FFN2 splitK=4
    reduce(Pb, M, Pd, 4, 1024, 0, b3, Uf, Xres, nullptr);
    layernorm_kernel<<<dim3(M), dim3(256), 0, stream>>>(Xres, g3, be3, Out, nullptr);
}